// Round 1
// baseline (1197.893 us; speedup 1.0000x reference)
//
#include <hip/hip_runtime.h>
#include <cstdint>
#include <cstddef>

#define M_DIM 2048
#define N_DIM 4096
#define K_DIM 20000
#define WF32_BYTES 327680000UL   /* 20000*4096*4 */
#define WBT_OFFSET 327680000UL   /* bf16 W^T lives after W_f32 */

typedef __attribute__((ext_vector_type(8))) short short8;
typedef __attribute__((ext_vector_type(4))) float float4v;
typedef __attribute__((ext_vector_type(8))) unsigned short ushort8;

__device__ __forceinline__ unsigned short f2bf_rne(float f) {
    union { float f; unsigned int u; } v; v.f = f;
    unsigned int u = v.u;
    u += 0x7FFFu + ((u >> 16) & 1u);   // round-to-nearest-even
    return (unsigned short)(u >> 16);
}

__device__ __forceinline__ void gload_lds16(const void* g, void* l) {
    __builtin_amdgcn_global_load_lds(
        (const __attribute__((address_space(1))) void*)g,
        (__attribute__((address_space(3))) void*)l, 16, 0, 0);
}

// ---- 1. scatter-add COO into dense fp32 W (K_DIM x N_DIM row-major) ----
__global__ void scatter_kernel(const float* __restrict__ kv,
                               const int* __restrict__ ind,
                               float* __restrict__ Wf32, int nnz) {
    int t = blockIdx.x * blockDim.x + threadIdx.x;
    if (t < nnz) {
        int r = ind[2 * t];
        int c = ind[2 * t + 1];
        atomicAdd(&Wf32[(size_t)r * N_DIM + c], kv[t]);
    }
}

// ---- 2. Wbt[n][k] = bf16(Wf32[k][n]) : tiled transpose + convert ----
__global__ void transpose_convert_kernel(const float* __restrict__ Wf32,
                                         unsigned short* __restrict__ Wbt) {
    __shared__ float tile[32][33];
    const int r0 = blockIdx.y * 32;   // K dim (625 tiles)
    const int c0 = blockIdx.x * 32;   // N dim (128 tiles)
    const int tx = threadIdx.x;       // 0..31
    const int ty = threadIdx.y;       // 0..7
    #pragma unroll
    for (int i = ty; i < 32; i += 8)
        tile[i][tx] = Wf32[(size_t)(r0 + i) * N_DIM + c0 + tx];
    __syncthreads();
    #pragma unroll
    for (int i = ty; i < 32; i += 8)
        Wbt[(size_t)(c0 + i) * K_DIM + r0 + tx] = f2bf_rne(tile[tx][i]);
}

// ---- 3. x fp32 -> bf16, 8 elements per thread ----
__global__ void convert_x_kernel(const float* __restrict__ x,
                                 unsigned short* __restrict__ xb) {
    size_t t = (size_t)blockIdx.x * 256 + threadIdx.x;
    const float4* xv = (const float4*)x;
    float4 a = xv[2 * t];
    float4 b = xv[2 * t + 1];
    ushort8 o;
    o[0] = f2bf_rne(a.x); o[1] = f2bf_rne(a.y);
    o[2] = f2bf_rne(a.z); o[3] = f2bf_rne(a.w);
    o[4] = f2bf_rne(b.x); o[5] = f2bf_rne(b.y);
    o[6] = f2bf_rne(b.z); o[7] = f2bf_rne(b.w);
    *(ushort8*)(xb + 8 * t) = o;
}

// ---- 4. C = tanh(A @ Bt^T + bias); A: MxK bf16, Bt: NxK bf16, C: MxN fp32 ----
// 128x128 block tile, BK=32, 4 waves in 2x2, each wave 64x64 via 4x4 16x16x32 MFMAs.
__global__ __launch_bounds__(256) void gemm_bt_kernel(
    const unsigned short* __restrict__ A,
    const unsigned short* __restrict__ Bt,
    const float* __restrict__ bias,
    float* __restrict__ C) {

    __shared__ unsigned short Als[128 * 32];   // [m][k], row = 64 B
    __shared__ unsigned short Bls[128 * 32];   // [n][k]

    const int t    = threadIdx.x;
    const int wid  = t >> 6;
    const int lane = t & 63;
    const int quad = lane >> 4;
    const int r16  = lane & 15;
    const int wm   = wid >> 1;
    const int wn   = wid & 1;

    const int m0 = blockIdx.y * 128;
    const int n0 = blockIdx.x * 128;

    // staging: chunk j in [0,512): m_local=j>>2, k_off=(j&3)*8 elems; LDS byte = j*16
    const unsigned short* gA0 = A  + (size_t)(m0 + (t >> 2)) * K_DIM + (t & 3) * 8;
    const unsigned short* gA1 = gA0 + (size_t)64 * K_DIM;
    const unsigned short* gB0 = Bt + (size_t)(n0 + (t >> 2)) * K_DIM + (t & 3) * 8;
    const unsigned short* gB1 = gB0 + (size_t)64 * K_DIM;

    char* lA0 = (char*)Als + wid * 1024;          // wave-uniform bases
    char* lA1 = (char*)Als + 4096 + wid * 1024;
    char* lB0 = (char*)Bls + wid * 1024;
    char* lB1 = (char*)Bls + 4096 + wid * 1024;

    const int abase = (wm * 64 + r16) * 64 + quad * 16;  // byte offset of A frag row-block 0
    const int bbase = (wn * 64 + r16) * 64 + quad * 16;

    float4v acc[4][4];
    #pragma unroll
    for (int i = 0; i < 4; ++i)
        #pragma unroll
        for (int j = 0; j < 4; ++j)
            acc[i][j] = (float4v){0.f, 0.f, 0.f, 0.f};

    for (int kt = 0; kt < K_DIM / 32; ++kt) {
        gload_lds16(gA0, lA0);
        gload_lds16(gA1, lA1);
        gload_lds16(gB0, lB0);
        gload_lds16(gB1, lB1);
        gA0 += 32; gA1 += 32; gB0 += 32; gB1 += 32;
        __syncthreads();

        short8 af[4], bfr[4];
        #pragma unroll
        for (int i = 0; i < 4; ++i)
            af[i] = *(const short8*)((const char*)Als + abase + i * 1024);
        #pragma unroll
        for (int j = 0; j < 4; ++j)
            bfr[j] = *(const short8*)((const char*)Bls + bbase + j * 1024);

        #pragma unroll
        for (int i = 0; i < 4; ++i)
            #pragma unroll
            for (int j = 0; j < 4; ++j)
                acc[i][j] = __builtin_amdgcn_mfma_f32_16x16x32_bf16(
                    af[i], bfr[j], acc[i][j], 0, 0, 0);
        __syncthreads();
    }

    // epilogue: C/D layout col = lane&15, row = quad*4 + reg
    #pragma unroll
    for (int i = 0; i < 4; ++i) {
        const int row = m0 + wm * 64 + i * 16 + quad * 4;
        #pragma unroll
        for (int j = 0; j < 4; ++j) {
            const int col = n0 + wn * 64 + j * 16 + r16;
            const float bb = bias[col];
            #pragma unroll
            for (int r = 0; r < 4; ++r)
                C[(size_t)(row + r) * N_DIM + col] = tanhf(acc[i][j][r] + bb);
        }
    }
}

extern "C" void kernel_launch(void* const* d_in, const int* in_sizes, int n_in,
                              void* d_out, int out_size, void* d_ws, size_t ws_size,
                              hipStream_t stream) {
    const float* x    = (const float*)d_in[0];
    const float* kv   = (const float*)d_in[1];
    const float* bias = (const float*)d_in[2];
    const int*   ind  = (const int*)d_in[3];
    const int nnz = in_sizes[1];

    float* Wf32 = (float*)d_ws;                                        // 327.68 MB
    unsigned short* Wbt = (unsigned short*)((char*)d_ws + WBT_OFFSET); // 163.84 MB
    unsigned short* xb  = (unsigned short*)d_ws;  // 81.92 MB, aliases Wf32 after it's dead

    // 1. zero dense W
    hipMemsetAsync(Wf32, 0, WF32_BYTES, stream);
    // 2. scatter (atomicAdd handles duplicate-index accumulation)
    scatter_kernel<<<(nnz + 255) / 256, 256, 0, stream>>>(kv, ind, Wf32, nnz);
    // 3. W^T bf16
    transpose_convert_kernel<<<dim3(N_DIM / 32, K_DIM / 32), dim3(32, 8), 0, stream>>>(Wf32, Wbt);
    // 4. x bf16 (after transpose consumed Wf32; stream order guarantees it)
    convert_x_kernel<<<(M_DIM * K_DIM) / (256 * 8), 256, 0, stream>>>(x, xb);
    // 5. GEMM + bias + tanh
    gemm_bt_kernel<<<dim3(N_DIM / 128, M_DIM / 128), 256, 0, stream>>>(
        xb, Wbt, bias, (float*)d_out);
}

// Round 2
// 993.560 us; speedup vs baseline: 1.2057x; 1.2057x over previous
//
#include <hip/hip_runtime.h>
#include <cstdint>
#include <cstddef>

#define M_DIM 2048
#define N_DIM 4096
#define K_DIM 20000
#define WF32_BYTES 327680000UL   /* 20000*4096*4 : fp32 W^T (N x K) */
#define WBT_OFFSET 327680000UL   /* bf16 W^T (N x K) lives after fp32 W^T */
#define XB_OFFSET  0UL           /* bf16 x aliases dead fp32 W^T region */
#define CP_OFFSET  81920000UL    /* 2x fp32 C-partials after xb, still inside old W^T region */
#define CP_BYTES   33554432UL    /* 2048*4096*4 */

typedef __attribute__((ext_vector_type(8))) short short8;
typedef __attribute__((ext_vector_type(4))) float float4v;
typedef __attribute__((ext_vector_type(8))) unsigned short ushort8;

__device__ __forceinline__ unsigned short f2bf_rne(float f) {
    union { float f; unsigned int u; } v; v.f = f;
    unsigned int u = v.u;
    u += 0x7FFFu + ((u >> 16) & 1u);   // round-to-nearest-even
    return (unsigned short)(u >> 16);
}

__device__ __forceinline__ void gload_lds16(const void* g, void* l) {
    __builtin_amdgcn_global_load_lds(
        (const __attribute__((address_space(1))) void*)g,
        (__attribute__((address_space(3))) void*)l, 16, 0, 0);
}

// ---- 1. scatter-add COO directly into fp32 W^T (N_DIM x K_DIM row-major) ----
__global__ void scatter_kernel(const float* __restrict__ kv,
                               const int* __restrict__ ind,
                               float* __restrict__ WT, int nnz) {
    int t = blockIdx.x * blockDim.x + threadIdx.x;
    if (t < nnz) {
        int r = ind[2 * t];      // input_dim index (K)
        int c = ind[2 * t + 1];  // units index (N)
        atomicAdd(&WT[(size_t)c * K_DIM + r], kv[t]);
    }
}

// ---- 2. streaming fp32 -> bf16 convert, 8 elements per thread ----
__global__ void convert_kernel(const float* __restrict__ src,
                               unsigned short* __restrict__ dst) {
    size_t t = (size_t)blockIdx.x * 256 + threadIdx.x;
    const float4* sv = (const float4*)src;
    float4 a = sv[2 * t];
    float4 b = sv[2 * t + 1];
    ushort8 o;
    o[0] = f2bf_rne(a.x); o[1] = f2bf_rne(a.y);
    o[2] = f2bf_rne(a.z); o[3] = f2bf_rne(a.w);
    o[4] = f2bf_rne(b.x); o[5] = f2bf_rne(b.y);
    o[6] = f2bf_rne(b.z); o[7] = f2bf_rne(b.w);
    *(ushort8*)(dst + 8 * t) = o;
}

// ---- 3. split-K GEMM partial: Cp[z] = A[:, kz] @ Bt[:, kz]^T (fp32 out, no epilogue)
// A: MxK bf16 row-major, Bt: NxK bf16 row-major.
// 128x128 block tile, BK=32, 4 waves in 2x2, each wave 64x64 via 4x4 16x16x32 MFMAs.
// blockIdx.z selects K-half: z=0 -> iters [0,312), z=1 -> iters [312,625).
__global__ __launch_bounds__(256) void gemm_bt_partial_kernel(
    const unsigned short* __restrict__ A,
    const unsigned short* __restrict__ Bt,
    float* __restrict__ Cp) {

    __shared__ unsigned short Als[128 * 32];   // [m][k], row = 64 B
    __shared__ unsigned short Bls[128 * 32];   // [n][k]

    const int t    = threadIdx.x;
    const int wid  = t >> 6;
    const int lane = t & 63;
    const int quad = lane >> 4;
    const int r16  = lane & 15;
    const int wm   = wid >> 1;
    const int wn   = wid & 1;

    const int m0 = blockIdx.y * 128;
    const int n0 = blockIdx.x * 128;
    const int z  = blockIdx.z;
    const int k0    = z ? 312 * 32 : 0;      // 9984
    const int iters = z ? 313 : 312;

    const unsigned short* gA0 = A  + (size_t)(m0 + (t >> 2)) * K_DIM + (t & 3) * 8 + k0;
    const unsigned short* gA1 = gA0 + (size_t)64 * K_DIM;
    const unsigned short* gB0 = Bt + (size_t)(n0 + (t >> 2)) * K_DIM + (t & 3) * 8 + k0;
    const unsigned short* gB1 = gB0 + (size_t)64 * K_DIM;

    char* lA0 = (char*)Als + wid * 1024;          // wave-uniform bases
    char* lA1 = (char*)Als + 4096 + wid * 1024;
    char* lB0 = (char*)Bls + wid * 1024;
    char* lB1 = (char*)Bls + 4096 + wid * 1024;

    const int abase = (wm * 64 + r16) * 64 + quad * 16;
    const int bbase = (wn * 64 + r16) * 64 + quad * 16;

    float4v acc[4][4];
    #pragma unroll
    for (int i = 0; i < 4; ++i)
        #pragma unroll
        for (int j = 0; j < 4; ++j)
            acc[i][j] = (float4v){0.f, 0.f, 0.f, 0.f};

    for (int kt = 0; kt < iters; ++kt) {
        gload_lds16(gA0, lA0);
        gload_lds16(gA1, lA1);
        gload_lds16(gB0, lB0);
        gload_lds16(gB1, lB1);
        gA0 += 32; gA1 += 32; gB0 += 32; gB1 += 32;
        __syncthreads();

        short8 af[4], bfr[4];
        #pragma unroll
        for (int i = 0; i < 4; ++i)
            af[i] = *(const short8*)((const char*)Als + abase + i * 1024);
        #pragma unroll
        for (int j = 0; j < 4; ++j)
            bfr[j] = *(const short8*)((const char*)Bls + bbase + j * 1024);

        #pragma unroll
        for (int i = 0; i < 4; ++i)
            #pragma unroll
            for (int j = 0; j < 4; ++j)
                acc[i][j] = __builtin_amdgcn_mfma_f32_16x16x32_bf16(
                    af[i], bfr[j], acc[i][j], 0, 0, 0);
        __syncthreads();
    }

    // write raw fp32 partial; C/D layout: col = lane&15, row = quad*4 + reg
    float* Cz = Cp + (size_t)z * M_DIM * N_DIM;
    #pragma unroll
    for (int i = 0; i < 4; ++i) {
        const int row = m0 + wm * 64 + i * 16 + quad * 4;
        #pragma unroll
        for (int j = 0; j < 4; ++j) {
            const int col = n0 + wn * 64 + j * 16 + r16;
            #pragma unroll
            for (int r = 0; r < 4; ++r)
                Cz[(size_t)(row + r) * N_DIM + col] = acc[i][j][r];
        }
    }
}

// ---- 4. combine: out = tanh(C0 + C1 + bias), float4 vectorized ----
__global__ void combine_kernel(const float* __restrict__ c0,
                               const float* __restrict__ c1,
                               const float* __restrict__ bias,
                               float* __restrict__ out) {
    size_t t = (size_t)blockIdx.x * 256 + threadIdx.x;       // per float4
    float4 a = ((const float4*)c0)[t];
    float4 b = ((const float4*)c1)[t];
    float4 bv = ((const float4*)bias)[t & (N_DIM / 4 - 1)];
    float4 o;
    o.x = tanhf(a.x + b.x + bv.x);
    o.y = tanhf(a.y + b.y + bv.y);
    o.z = tanhf(a.z + b.z + bv.z);
    o.w = tanhf(a.w + b.w + bv.w);
    ((float4*)out)[t] = o;
}

extern "C" void kernel_launch(void* const* d_in, const int* in_sizes, int n_in,
                              void* d_out, int out_size, void* d_ws, size_t ws_size,
                              hipStream_t stream) {
    const float* x    = (const float*)d_in[0];
    const float* kv   = (const float*)d_in[1];
    const float* bias = (const float*)d_in[2];
    const int*   ind  = (const int*)d_in[3];
    const int nnz = in_sizes[1];

    float* Wf32T = (float*)d_ws;                                        // 327.68 MB
    unsigned short* Wbt = (unsigned short*)((char*)d_ws + WBT_OFFSET);  // 163.84 MB
    unsigned short* xb  = (unsigned short*)((char*)d_ws + XB_OFFSET);   // 81.92 MB (aliases dead Wf32T)
    float* Cp = (float*)((char*)d_ws + CP_OFFSET);                      // 2 x 33.55 MB (aliases dead Wf32T)

    // 1. zero dense fp32 W^T
    hipMemsetAsync(Wf32T, 0, WF32_BYTES, stream);
    // 2. scatter into W^T layout (atomicAdd handles duplicate-index accumulation)
    scatter_kernel<<<(nnz + 255) / 256, 256, 0, stream>>>(kv, ind, Wf32T, nnz);
    // 3. straight convert fp32 W^T -> bf16 W^T (full-BW streaming)
    convert_kernel<<<(N_DIM * K_DIM) / (256 * 8), 256, 0, stream>>>(Wf32T, Wbt);
    // 4. x fp32 -> bf16 (Wf32T is dead from here; xb/Cp alias it)
    convert_kernel<<<(M_DIM * K_DIM) / (256 * 8), 256, 0, stream>>>(x, xb);
    // 5. split-K=2 GEMM partials (grid 1024 -> 4 blocks/CU resident)
    gemm_bt_partial_kernel<<<dim3(N_DIM / 128, M_DIM / 128, 2), 256, 0, stream>>>(
        xb, Wbt, Cp);
    // 6. combine + bias + tanh
    combine_kernel<<<(M_DIM * N_DIM) / (256 * 4), 256, 0, stream>>>(
        Cp, Cp + (size_t)M_DIM * N_DIM, bias, (float*)d_out);
}

// Round 3
// 866.831 us; speedup vs baseline: 1.3819x; 1.1462x over previous
//
#include <hip/hip_runtime.h>
#include <cstdint>
#include <cstddef>

#define M_DIM 2048
#define N_DIM 4096
#define K_DIM 20000
#define WBT_BYTES 163840000UL    /* 4096*20000*2 : bf16 W^T (N x K), built in-place */
#define XB_OFFSET 163840000UL    /* bf16 x after Wbt */
#define CP_OFFSET 245760000UL    /* 4x fp32 C-partials after xb */

typedef __attribute__((ext_vector_type(8))) short short8;
typedef __attribute__((ext_vector_type(4))) float float4v;
typedef __attribute__((ext_vector_type(8))) unsigned short ushort8;

__device__ __forceinline__ unsigned short f2bf_rne(float f) {
    union { float f; unsigned int u; } v; v.f = f;
    unsigned int u = v.u;
    u += 0x7FFFu + ((u >> 16) & 1u);   // round-to-nearest-even
    return (unsigned short)(u >> 16);
}

__device__ __forceinline__ float bf2f(unsigned short h) {
    union { unsigned int u; float f; } v;
    v.u = ((unsigned int)h) << 16;
    return v.f;
}

__device__ __forceinline__ void gload_lds16(const void* g, void* l) {
    __builtin_amdgcn_global_load_lds(
        (const __attribute__((address_space(1))) void*)g,
        (__attribute__((address_space(3))) void*)l, 16, 0, 0);
}

// ---- 1. scatter-add COO directly into bf16 W^T (N_DIM x K_DIM row-major) ----
// 16-bit half update via 32-bit CAS loop. Word collisions are rare (~49k of 2M),
// duplicate-index accumulation preserved (extra bf16 rounding on dups ~2e-4, negligible).
__global__ void scatter_bf16_kernel(const float* __restrict__ kv,
                                    const int* __restrict__ ind,
                                    unsigned int* __restrict__ W, int nnz) {
    int t = blockIdx.x * blockDim.x + threadIdx.x;
    if (t >= nnz) return;
    int r = ind[2 * t];      // input_dim index (K)
    int c = ind[2 * t + 1];  // units index (N)
    float v = kv[t];
    size_t elem = (size_t)c * K_DIM + r;   // bf16 element index in W^T
    unsigned int* word = &W[elem >> 1];
    const bool hi = (elem & 1) != 0;       // K_DIM even -> rows never straddle words
    unsigned int old = __atomic_load_n(word, __ATOMIC_RELAXED);
    unsigned int assumed;
    do {
        assumed = old;
        unsigned short h = hi ? (unsigned short)(assumed >> 16)
                              : (unsigned short)(assumed & 0xFFFFu);
        unsigned short nh = f2bf_rne(bf2f(h) + v);
        unsigned int nw = hi ? ((assumed & 0x0000FFFFu) | ((unsigned int)nh << 16))
                             : ((assumed & 0xFFFF0000u) | (unsigned int)nh);
        old = atomicCAS(word, assumed, nw);
    } while (old != assumed);
}

// ---- 2. streaming fp32 -> bf16 convert (for x), 8 elements per thread ----
__global__ void convert_kernel(const float* __restrict__ src,
                               unsigned short* __restrict__ dst) {
    size_t t = (size_t)blockIdx.x * 256 + threadIdx.x;
    const float4* sv = (const float4*)src;
    float4 a = sv[2 * t];
    float4 b = sv[2 * t + 1];
    ushort8 o;
    o[0] = f2bf_rne(a.x); o[1] = f2bf_rne(a.y);
    o[2] = f2bf_rne(a.z); o[3] = f2bf_rne(a.w);
    o[4] = f2bf_rne(b.x); o[5] = f2bf_rne(b.y);
    o[6] = f2bf_rne(b.z); o[7] = f2bf_rne(b.w);
    *(ushort8*)(dst + 8 * t) = o;
}

// ---- 3. split-K=4 GEMM partial: Cp[z] = A[:, kz] @ Bt[:, kz]^T (fp32, no epilogue)
// A: MxK bf16 row-major, Bt: NxK bf16 row-major.
// 128x128 block tile, BK=32, 4 waves in 2x2, each wave 64x64 via 4x4 16x16x32 MFMAs.
// K-iters per z: {157,156,156,156} (sum 625 = 20000/32).
__global__ __launch_bounds__(256) void gemm_bt_partial_kernel(
    const unsigned short* __restrict__ A,
    const unsigned short* __restrict__ Bt,
    float* __restrict__ Cp) {

    __shared__ unsigned short Als[128 * 32];   // [m][k], row = 64 B
    __shared__ unsigned short Bls[128 * 32];   // [n][k]

    const int t    = threadIdx.x;
    const int wid  = t >> 6;
    const int lane = t & 63;
    const int quad = lane >> 4;
    const int r16  = lane & 15;
    const int wm   = wid >> 1;
    const int wn   = wid & 1;

    const int m0 = blockIdx.y * 128;
    const int n0 = blockIdx.x * 128;
    const int z  = blockIdx.z;
    const int iters = z ? 156 : 157;
    const int k0 = (z ? (157 + 156 * (z - 1)) : 0) * 32;

    const unsigned short* gA0 = A  + (size_t)(m0 + (t >> 2)) * K_DIM + (t & 3) * 8 + k0;
    const unsigned short* gA1 = gA0 + (size_t)64 * K_DIM;
    const unsigned short* gB0 = Bt + (size_t)(n0 + (t >> 2)) * K_DIM + (t & 3) * 8 + k0;
    const unsigned short* gB1 = gB0 + (size_t)64 * K_DIM;

    char* lA0 = (char*)Als + wid * 1024;          // wave-uniform bases
    char* lA1 = (char*)Als + 4096 + wid * 1024;
    char* lB0 = (char*)Bls + wid * 1024;
    char* lB1 = (char*)Bls + 4096 + wid * 1024;

    const int abase = (wm * 64 + r16) * 64 + quad * 16;
    const int bbase = (wn * 64 + r16) * 64 + quad * 16;

    float4v acc[4][4];
    #pragma unroll
    for (int i = 0; i < 4; ++i)
        #pragma unroll
        for (int j = 0; j < 4; ++j)
            acc[i][j] = (float4v){0.f, 0.f, 0.f, 0.f};

    for (int kt = 0; kt < iters; ++kt) {
        gload_lds16(gA0, lA0);
        gload_lds16(gA1, lA1);
        gload_lds16(gB0, lB0);
        gload_lds16(gB1, lB1);
        gA0 += 32; gA1 += 32; gB0 += 32; gB1 += 32;
        __syncthreads();

        short8 af[4], bfr[4];
        #pragma unroll
        for (int i = 0; i < 4; ++i)
            af[i] = *(const short8*)((const char*)Als + abase + i * 1024);
        #pragma unroll
        for (int j = 0; j < 4; ++j)
            bfr[j] = *(const short8*)((const char*)Bls + bbase + j * 1024);

        #pragma unroll
        for (int i = 0; i < 4; ++i)
            #pragma unroll
            for (int j = 0; j < 4; ++j)
                acc[i][j] = __builtin_amdgcn_mfma_f32_16x16x32_bf16(
                    af[i], bfr[j], acc[i][j], 0, 0, 0);
        __syncthreads();
    }

    // write raw fp32 partial; C/D layout: col = lane&15, row = quad*4 + reg
    float* Cz = Cp + (size_t)z * M_DIM * N_DIM;
    #pragma unroll
    for (int i = 0; i < 4; ++i) {
        const int row = m0 + wm * 64 + i * 16 + quad * 4;
        #pragma unroll
        for (int j = 0; j < 4; ++j) {
            const int col = n0 + wn * 64 + j * 16 + r16;
            #pragma unroll
            for (int r = 0; r < 4; ++r)
                Cz[(size_t)(row + r) * N_DIM + col] = acc[i][j][r];
        }
    }
}

// ---- 4. combine: out = tanh(C0 + C1 + C2 + C3 + bias), float4 vectorized ----
__global__ void combine_kernel(const float* __restrict__ Cp,
                               const float* __restrict__ bias,
                               float* __restrict__ out) {
    size_t t = (size_t)blockIdx.x * 256 + threadIdx.x;       // per float4
    const size_t stride = (size_t)M_DIM * N_DIM / 4;
    float4 a = ((const float4*)Cp)[t];
    float4 b = ((const float4*)Cp)[t + stride];
    float4 c = ((const float4*)Cp)[t + 2 * stride];
    float4 d = ((const float4*)Cp)[t + 3 * stride];
    float4 bv = ((const float4*)bias)[t & (N_DIM / 4 - 1)];
    float4 o;
    o.x = tanhf(a.x + b.x + c.x + d.x + bv.x);
    o.y = tanhf(a.y + b.y + c.y + d.y + bv.y);
    o.z = tanhf(a.z + b.z + c.z + d.z + bv.z);
    o.w = tanhf(a.w + b.w + c.w + d.w + bv.w);
    ((float4*)out)[t] = o;
}

extern "C" void kernel_launch(void* const* d_in, const int* in_sizes, int n_in,
                              void* d_out, int out_size, void* d_ws, size_t ws_size,
                              hipStream_t stream) {
    const float* x    = (const float*)d_in[0];
    const float* kv   = (const float*)d_in[1];
    const float* bias = (const float*)d_in[2];
    const int*   ind  = (const int*)d_in[3];
    const int nnz = in_sizes[1];

    unsigned short* Wbt = (unsigned short*)d_ws;                        // 163.84 MB bf16 W^T
    unsigned short* xb  = (unsigned short*)((char*)d_ws + XB_OFFSET);   // 81.92 MB bf16 x
    float* Cp = (float*)((char*)d_ws + CP_OFFSET);                      // 4 x 33.55 MB partials

    // 1. zero bf16 W^T (164 MB -> L3-resident for the scatter)
    hipMemsetAsync(Wbt, 0, WBT_BYTES, stream);
    // 2. scatter-add straight into bf16 W^T (CAS on 16-bit halves)
    scatter_bf16_kernel<<<(nnz + 255) / 256, 256, 0, stream>>>(
        kv, ind, (unsigned int*)Wbt, nnz);
    // 3. x fp32 -> bf16
    convert_kernel<<<(M_DIM * K_DIM) / (256 * 8), 256, 0, stream>>>(x, xb);
    // 4. split-K=4 GEMM partials
    gemm_bt_partial_kernel<<<dim3(N_DIM / 128, M_DIM / 128, 4), 256, 0, stream>>>(
        xb, Wbt, Cp);
    // 5. combine + bias + tanh
    combine_kernel<<<(M_DIM * N_DIM) / (256 * 4), 256, 0, stream>>>(
        Cp, bias, (float*)d_out);
}